// Round 5
// baseline (478.975 us; speedup 1.0000x reference)
//
#include <hip/hip_runtime.h>
#include <float.h>
#include <math.h>

#define THREADS 256
#define CAP 1536            // LDS candidate buffer entries
#define ROWS_PER_BLOCK 2

typedef float f32x4 __attribute__((ext_vector_type(4)));
typedef unsigned short u16;
typedef u16 u16x8 __attribute__((ext_vector_type(8)));

// (v, idx) comparator implementing lax.top_k order: larger value wins,
// ties broken by LOWER index.
__device__ __forceinline__ bool better(float av, int ai, float bv, int bi) {
    return av > bv || (av == bv && ai < bi);
}

// ---------------------------------------------------------------------------
// Deterministic block reductions (256 threads = 4 waves of 64).
// ---------------------------------------------------------------------------
__device__ __forceinline__ void block_argmax(float& v, int& idx, float* wv, int* wi, int tid) {
    #pragma unroll
    for (int m = 32; m >= 1; m >>= 1) {
        float ov = __shfl_xor(v, m, 64);
        int   oi = __shfl_xor(idx, m, 64);
        if (better(ov, oi, v, idx)) { v = ov; idx = oi; }
    }
    if ((tid & 63) == 0) { wv[tid >> 6] = v; wi[tid >> 6] = idx; }
    __syncthreads();
    if (tid == 0) {
        float bv = wv[0]; int bi = wi[0];
        #pragma unroll
        for (int w = 1; w < 4; ++w) {
            if (better(wv[w], wi[w], bv, bi)) { bv = wv[w]; bi = wi[w]; }
        }
        wv[0] = bv; wi[0] = bi;
    }
    __syncthreads();
    v = wv[0]; idx = wi[0];
    __syncthreads();
}

__device__ __forceinline__ float block_sum(float v, float* wv, int tid) {
    #pragma unroll
    for (int m = 32; m >= 1; m >>= 1) v += __shfl_xor(v, m, 64);
    if ((tid & 63) == 0) wv[tid >> 6] = v;
    __syncthreads();
    if (tid == 0) wv[0] = wv[0] + wv[1] + wv[2] + wv[3];
    __syncthreads();
    float r = wv[0];
    __syncthreads();
    return r;
}

// ---------------------------------------------------------------------------
// Kernel A: W[HH][S] fp32 -> Wtb[S][HH] bf16 (RNE). Halves transpose write
// and (more importantly) the dot phase's L2/L3 read volume.
// ---------------------------------------------------------------------------
__global__ __launch_bounds__(256) void transposeW_bf16(const float* __restrict__ W,
                                                       u16* __restrict__ Wtb,
                                                       int S, int HH) {
    __shared__ float tile[32][33];
    int x  = blockIdx.x * 32 + threadIdx.x;
    int y0 = blockIdx.y * 32;
    #pragma unroll
    for (int i = threadIdx.y; i < 32; i += 8) {
        int h = y0 + i;
        if (x < S && h < HH) tile[i][threadIdx.x] = W[(size_t)h * S + x];
    }
    __syncthreads();
    #pragma unroll
    for (int i = threadIdx.y; i < 32; i += 8) {
        int s = blockIdx.x * 32 + i;
        int h = y0 + threadIdx.x;
        if (s < S && h < HH) {
            unsigned u = __float_as_uint(tile[threadIdx.x][i]);
            unsigned r = (u + 0x7fffu + ((u >> 16) & 1u)) >> 16;   // RNE bf16
            Wtb[(size_t)s * HH + h] = (u16)r;
        }
    }
}

// ---------------------------------------------------------------------------
// Fused per-row kernel, 2 rows/block.
// Stream: copy + fill + threshold-append top-8 candidates (cheap VALU).
// Epilogue: exact top-8 compaction, gather, dedup, owner-compacted bf16 dots
// (2 senses per wave-load), slot-ordered softmax, delta, scatter.
// ---------------------------------------------------------------------------
__global__ __launch_bounds__(THREADS) void fused_row(const float* __restrict__ hidden,
                                                     const float* __restrict__ pg,
                                                     const u16* __restrict__ Wtb,
                                                     const float* __restrict__ bias,
                                                     const int* __restrict__ graph,
                                                     float* __restrict__ outg,
                                                     float* __restrict__ outS,
                                                     int S, int V, int NBR) {
    __shared__ __align__(16) float sh_h[256];
    __shared__ float cbv[CAP];
    __shared__ int   cbi[CAP];
    __shared__ float t8v[8];
    __shared__ int   t8i[8];
    __shared__ int   cand[256];
    __shared__ float slog[256];
    __shared__ int   ol_s[256];
    __shared__ int   ol_t[256];
    __shared__ float wv[4];
    __shared__ int   wi[4];
    __shared__ int   ccnt, ocnt;

    const int tid  = threadIdx.x;
    const int lane = tid & 63;
    const float LOGEPS = -18.420680743952367f;   // logf(1e-8f)

    for (int rr = 0; rr < ROWS_PER_BLOCK; ++rr) {
        const int row = blockIdx.x * ROWS_PER_BLOCK + rr;

        // ---- per-row init
        if (tid < 8) { t8v[tid] = -FLT_MAX; t8i[tid] = 0x7fffffff; }
        if (tid == 0) ocnt = 0;
        sh_h[tid] = hidden[(size_t)row * 256 + tid];
        __syncthreads();

        // ---- stream phase: copy + fill + candidate scan
        const f32x4* in4  = (const f32x4*)(pg   + (size_t)row * V);
        f32x4*       out4 = (f32x4*)(outg + (size_t)row * V);
        f32x4*       o4   = (f32x4*)(outS + (size_t)row * S);
        const f32x4 fill4 = { LOGEPS, LOGEPS, LOGEPS, LOGEPS };
        const int nv4 = V >> 2, nS4 = S >> 2;
        const int niter = (nv4 + THREADS - 1) / THREADS;
        float thr = -FLT_MAX;

        for (int j = 0; j < niter; ++j) {
            const int i = j * THREADS + tid;
            if (i < nv4) {
                f32x4 val = __builtin_nontemporal_load(in4 + i);
                __builtin_nontemporal_store(val, out4 + i);
                if (i < nS4) __builtin_nontemporal_store(fill4, o4 + i);
                const int base = i << 2;
                if (j == 0) {                       // seed: first 1024 elements verbatim
                    #pragma unroll
                    for (int c = 0; c < 4; ++c) { cbv[(tid << 2) | c] = val[c]; cbi[(tid << 2) | c] = base + c; }
                } else {
                    #pragma unroll
                    for (int c = 0; c < 4; ++c) {
                        float v = val[c];
                        if (v >= thr) {             // >=: value-ties must compete by index
                            int pos = atomicAdd(&ccnt, 1);
                            if (pos < CAP) { cbv[pos] = v; cbi[pos] = base + c; }
                        }
                    }
                }
            }
            if (j == niter - 1) {                   // scalar tails (0 iterations for 30000)
                for (int i2 = (nv4 << 2) + tid; i2 < V; i2 += THREADS) {
                    float v = pg[(size_t)row * V + i2];
                    outg[(size_t)row * V + i2] = v;
                    if (v >= thr) {
                        int pos = atomicAdd(&ccnt, 1);
                        if (pos < CAP) { cbv[pos] = v; cbi[pos] = i2; }
                    }
                }
                for (int i2 = (nS4 << 2) + tid; i2 < S; i2 += THREADS)
                    outS[(size_t)row * S + i2] = LOGEPS;
            }
            __syncthreads();
            const int cc = (j == 0) ? 4 * min(nv4, THREADS) : min(ccnt, CAP);
            // compact: always at j==0 (seed -> threshold), near-capacity (uniform,
            // guarantees appends never exceed CAP), and at the last iteration.
            if (j == 0 || cc >= CAP - 4 * THREADS || j == niter - 1) {
                float tv[8]; int ti[8];
                #pragma unroll
                for (int p = 0; p < 8; ++p) { tv[p] = -FLT_MAX; ti[p] = 0x7fffffff; }
                for (int k = tid; k < 8 + cc; k += THREADS) {   // virtual [t8 | cbuf]
                    float v; int ix;
                    if (k < 8) { v = t8v[k]; ix = t8i[k]; } else { v = cbv[k - 8]; ix = cbi[k - 8]; }
                    if (better(v, ix, tv[7], ti[7])) {
                        tv[7] = v; ti[7] = ix;
                        #pragma unroll
                        for (int p = 7; p > 0; --p) {
                            if (better(tv[p], ti[p], tv[p - 1], ti[p - 1])) {
                                float tf = tv[p]; tv[p] = tv[p - 1]; tv[p - 1] = tf;
                                int   tt = ti[p]; ti[p] = ti[p - 1]; ti[p - 1] = tt;
                            }
                        }
                    }
                }
                __syncthreads();                    // t8 fully consumed before overwrite
                for (int r = 0; r < 8; ++r) {
                    float v = tv[0]; int ix = ti[0];
                    block_argmax(v, ix, wv, wi, tid);
                    if (ti[0] == ix) {              // unique owner pops its head
                        #pragma unroll
                        for (int p = 0; p < 7; ++p) { tv[p] = tv[p + 1]; ti[p] = ti[p + 1]; }
                        tv[7] = -FLT_MAX; ti[7] = 0x7fffffff;
                    }
                    if (tid == 0) { t8v[r] = v; t8i[r] = ix; }
                }
                if (tid == 0) ccnt = 0;
                __syncthreads();
                thr = t8v[7];
            }
        }

        // ---- gather candidate neighbours: 8 topk rows x 32 nbrs, coalesced
        const int j8 = tid >> 5, c32 = tid & 31;
        int my = -1;
        if (c32 < NBR) {
            int g = graph[(size_t)(t8i[j8] + S) * NBR + c32] - 1;
            my = (g >= 0 && g < S) ? g : -1;
        }
        cand[tid] = my;
        __syncthreads();

        // ---- dedup (owner = lowest slot with this sense) + owner compaction
        bool owner = (my >= 0);
        if (owner) {
            for (int t = 0; t < tid; ++t) {
                if (cand[t] == my) { owner = false; break; }
            }
        }
        if (owner) {
            int pos = atomicAdd(&ocnt, 1);          // order nondet; results keyed by slot
            ol_s[pos] = my; ol_t[pos] = tid;
        }
        __syncthreads();
        int nsel = ocnt;
        if (nsel == 0) {                            // zero-neighbour fallback: sense 0
            if (tid == 0) { ol_s[0] = 0; ol_t[0] = 0; owner = true; my = 0; }
            nsel = 1;
            __syncthreads();
        }
        const int nowners = nsel;

        // ---- owner-compacted bf16 dots: each wave loads 2 senses (1KB), each
        //      32-lane half reduces one sense; logit -> slog[original slot].
        {
            const int wid2 = (tid >> 6) << 1;       // {0,2,4,6}
            const int half = lane >> 5;             // 0 | 1
            const int l32  = lane & 31;
            const f32x4 hA = ((const f32x4*)sh_h)[l32 * 2];
            const f32x4 hB = ((const f32x4*)sh_h)[l32 * 2 + 1];
            for (int i = wid2; i < nowners; i += 8) {
                const int iB = (i + 1 < nowners) ? i + 1 : i;
                const int sense = half ? ol_s[iB] : ol_s[i];
                const u16x8 w8 = *(const u16x8*)(Wtb + (size_t)sense * 256 + l32 * 8);
                float acc = 0.f;
                #pragma unroll
                for (int c = 0; c < 8; ++c) {
                    float wf = __uint_as_float(((unsigned)w8[c]) << 16);
                    float hf = (c < 4) ? hA[c] : hB[c - 4];
                    acc = fmaf(wf, hf, acc);
                }
                #pragma unroll
                for (int m = 16; m >= 1; m >>= 1) acc += __shfl_xor(acc, m, 64);
                if (l32 == 0) slog[half ? ol_t[iB] : ol_t[i]] = acc + bias[sense];
            }
        }
        __syncthreads();

        // ---- slot-ordered softmax (deterministic), delta at argmax, scatter
        const float logit = owner ? slog[tid] : -FLT_MAX;
        float mv = logit;
        int   ai = owner ? my : 0x7fffffff;
        block_argmax(mv, ai, wv, wi, tid);          // tie -> lowest sense (ref argmax)

        const float e = owner ? expf(logit - mv) : 0.f;
        const float sum = block_sum(e, wv, tid);
        // barriers above drained the fill stores -> scatter overwrites are safe
        if (owner) {
            float p = e / sum;
            if (my == ai) p -= 1e-8f * (float)(S - nsel);
            outS[(size_t)row * S + my] = logf(p);
        }
        __syncthreads();                            // protect LDS re-init next row
    }
}

// ---------------------------------------------------------------------------
extern "C" void kernel_launch(void* const* d_in, const int* in_sizes, int n_in,
                              void* d_out, int out_size, void* d_ws, size_t ws_size,
                              hipStream_t stream) {
    const float* hidden = (const float*)d_in[0];
    const float* pg     = (const float*)d_in[1];
    const float* W      = (const float*)d_in[2];
    const float* bias   = (const float*)d_in[3];
    const int*   graph  = (const int*)d_in[4];
    // d_in[5] is K; fixed at 8 by the problem spec.

    const int S   = in_sizes[3];
    const int HH  = in_sizes[2] / S;   // 256
    const int N   = in_sizes[0] / HH;
    const int V   = in_sizes[1] / N;
    const int NBR = in_sizes[4] / (S + V);

    u16* Wtb = (u16*)d_ws;             // S*HH bf16

    float* outg = (float*)d_out;
    float* outS = outg + (size_t)N * V;

    dim3 tb(32, 8);
    dim3 tg((S + 31) / 32, (HH + 31) / 32);
    transposeW_bf16<<<tg, tb, 0, stream>>>(W, Wtb, S, HH);
    fused_row<<<N / ROWS_PER_BLOCK, THREADS, 0, stream>>>(hidden, pg, Wtb, bias, graph,
                                                          outg, outS, S, V, NBR);
}